// Round 3
// baseline (2996.063 us; speedup 1.0000x reference)
//
#include <hip/hip_runtime.h>
#include <math.h>

#define DDIM 64
#define TILE 128
#define NTH 256
#define KSTEP 32                  // floats staged per K-step
#define RSTRIDE 36                // LDS row stride in floats: 32 + 4 pad.
// Stride 36 (=144B, 16B-aligned) rotates each row's bank start by 4 banks:
// bank-group of (row, g) = (row + g) mod 8. Wave read patterns:
//   a-reads: 4 distinct ty -> 4 distinct groups, 16-lane broadcast: conflict-free
//   b-reads: 16 tx -> each group hit by 2 addrs: 2-way (free, m136)
//   staging writes: (r+g) mod 8 uniform over 64 lanes: minimal aliasing
// No XOR swizzle -> every LDS address is base VGPR + compile-time immediate.

// ---------------------------------------------------------------------------
// L1-distance + exp, 128x128 tile, 256 threads, 8x8 outputs/thread.
// Mean adjustment dropped: |(x1-m) - (x2-m)| == |x1 - x2| exactly; fp rounding
// difference ~64*eps*|x| -> ~2e-22 in the output, 3 orders under threshold.
// D split into 2 K-steps of 32 floats -> LDS 36KB/block -> 4 blocks/CU.
// ---------------------------------------------------------------------------
__global__ __launch_bounds__(NTH, 4) void laplace_tile_kernel(
    const float* __restrict__ x1, const float* __restrict__ x2,
    const float* __restrict__ lsp, float* __restrict__ out, int M) {
  __shared__ float at[TILE * RSTRIDE];
  __shared__ float bt[TILE * RSTRIDE];

  const int tid = threadIdx.x;
  const int ty = tid >> 4;                 // 0..15: owns rows 16r+ty
  const int tx = tid & 15;                 // 0..15: owns cols 16c+tx
  const int row0 = blockIdx.y * TILE;
  const int col0 = blockIdx.x * TILE;
  const float rls = 1.0f / lsp[0];         // THETA(=1) * lengthscale

  // staging assignment: 4 float4 per tile per thread
  const int sg = tid & 7;                  // float4 group 0..7
  const int sr = tid >> 3;                 // row 0..31 (stripe base)

  float acc[8][8];
  #pragma unroll
  for (int r = 0; r < 8; ++r)
    #pragma unroll
    for (int c = 0; c < 8; ++c) acc[r][c] = 0.f;

  for (int h = 0; h < 2; ++h) {
    __syncthreads();                       // protect LDS from previous step
    // ---- stage K-slice [32h, 32h+32) of both tiles, scaled by 1/ls ----
    #pragma unroll
    for (int s = 0; s < 4; ++s) {
      const int r = sr + 32 * s;
      float4 va = *(const float4*)&x1[(size_t)(row0 + r) * DDIM + h * KSTEP + sg * 4];
      float4 vb = *(const float4*)&x2[(size_t)(col0 + r) * DDIM + h * KSTEP + sg * 4];
      va.x *= rls; va.y *= rls; va.z *= rls; va.w *= rls;
      vb.x *= rls; vb.y *= rls; vb.z *= rls; vb.w *= rls;
      *(float4*)&at[r * RSTRIDE + sg * 4] = va;
      *(float4*)&bt[r * RSTRIDE + sg * 4] = vb;
    }
    __syncthreads();

    // ---- accumulate over this K-slice: 8 float4 groups ----
    const float4* __restrict__ arow = (const float4*)&at[ty * RSTRIDE];
    const float4* __restrict__ brow = (const float4*)&bt[tx * RSTRIDE];
    // arow[(16*r*RSTRIDE)/4 + g] : all offsets are compile-time immediates
    #pragma unroll
    for (int g = 0; g < 8; ++g) {
      float4 b[8];
      #pragma unroll
      for (int c = 0; c < 8; ++c)
        b[c] = brow[c * 4 * RSTRIDE + g];  // row 16c+tx, group g
      #pragma unroll
      for (int r = 0; r < 8; ++r) {
        const float4 a = arow[r * 4 * RSTRIDE + g];  // row 16r+ty, group g
        #pragma unroll
        for (int c = 0; c < 8; ++c) {
          const float s01 = fabsf(a.x - b[c].x) + fabsf(a.y - b[c].y);
          const float s23 = fabsf(a.z - b[c].z) + fabsf(a.w - b[c].w);
          acc[r][c] += s01 + s23;
        }
      }
    }
  }

  // ---- epilogue: clamp, fast exp, store ----
  #pragma unroll
  for (int r = 0; r < 8; ++r) {
    const size_t orow = (size_t)(row0 + 16 * r + ty) * (size_t)M + col0 + tx;
    #pragma unroll
    for (int c = 0; c < 8; ++c) {
      out[orow + 16 * c] = __expf(-fmaxf(acc[r][c], 1e-15f));
    }
  }
}

// ---------------------------------------------------------------------------
extern "C" void kernel_launch(void* const* d_in, const int* in_sizes, int n_in,
                              void* d_out, int out_size, void* d_ws, size_t ws_size,
                              hipStream_t stream) {
  const float* x1 = (const float*)d_in[0];
  const float* x2 = (const float*)d_in[1];
  const float* ls = (const float*)d_in[2];
  float* out = (float*)d_out;

  const int N = in_sizes[0] / DDIM;
  const int M = in_sizes[1] / DDIM;

  dim3 grid(M / TILE, N / TILE);
  laplace_tile_kernel<<<grid, NTH, 0, stream>>>(x1, x2, ls, out, M);
}